// Round 8
// baseline (98.423 us; speedup 1.0000x reference)
//
#include <hip/hip_runtime.h>
#include <hip/hip_bf16.h>
#include <math.h>

// Symmetric Hausdorff, B=8, N=M=4096, D=2, fp32.
// Round 8: R7 post-mortem — pk'ing the inner loop shrank the VALU window but
// kept 1 ds_read_b128/iter/wave -> LDS pipe ~90%+, neutral. Fix: amortize the
// LDS read over IB=16 i-points (one thread owns its whole lane-column; no ib
// split) AND keep packed fp32. Per j-iter: 1 b128 + 2 pk + 16*(2 v_pk_fma_f32
// + v_min3) = 51 inst -> LDS ~47%, 1.56 inst/pair, floor ~8.1 us. LDS staged
// pre-swizzled (x0,x1,y0,y1) so qx/qy are adjacent VGPR pairs (no pack movs).
// JC=64 restores 1024 blocks (4/CU). maxred+final fused via last-block-of-256
// (atomic slots + one lane-0 __threadfence per block; read-only kernel so the
// fence's L2 writeback is near-free, unlike R6's 1024 fences over dirty pw).
// The ~42us fillBuffer in every profile is the harness poisoning the 256 MiB
// workspace inside the timed window — fixed cost, not ours.

#define B 8
#define N 4096
#define TPB 256
#define IB 16             // i-points per thread (covers all 4096 i per block)
#define JC 64             // j-chunks per (b,dir)
#define JTILE (N / JC)    // 64 j-points per block
#define ITILES (N / TPB)  // 16 i-tiles for the reduce stage
#define RBLOCKS (ITILES * B * 2)   // 256 reduce blocks

typedef float v2f __attribute__((ext_vector_type(2)));

__global__ __launch_bounds__(TPB, 4) void hk_partial(const float* __restrict__ pred,
                                                     const float* __restrict__ target,
                                                     float* __restrict__ pw) {
    const int jc  = blockIdx.x;        // 0..63
    const int b   = blockIdx.y;
    const int dir = blockIdx.z;
    const int t   = threadIdx.x;

    const float2* __restrict__ P =
        reinterpret_cast<const float2*>(dir == 0 ? pred : target) + (size_t)b * N;
    const float*  __restrict__ Qf =
        (dir == 0 ? target : pred) + (size_t)b * N * 2 + (size_t)jc * JTILE * 2;

    // Stage 64 j-points as 32 float4, swizzled (x0,x1,y0,y1) so the packed
    // loop's qx/qy fall in adjacent VGPR pairs. 512 B LDS.
    __shared__ float4 sQ[JTILE / 2];
    if (t < JTILE / 2) {
        float4 g = reinterpret_cast<const float4*>(Qf)[t];   // x0,y0,x1,y1
        sQ[t] = make_float4(g.x, g.z, g.y, g.w);             // x0,x1,y0,y1
    }
    __syncthreads();

    // This thread's 16 source points (strided by TPB so pw stores coalesce).
    v2f m2x[IB], m2y[IB];
    float pp[IB], mn[IB];
    #pragma unroll
    for (int k = 0; k < IB; ++k) {
        float2 p = P[t + k * TPB];
        float ax = -2.f * p.x, ay = -2.f * p.y;
        m2x[k] = (v2f){ax, ax};
        m2y[k] = (v2f){ay, ay};
        pp[k]  = fmaf(p.x, p.x, p.y * p.y);
        mn[k]  = 3.402823466e38f;
    }

    // min_j(|q|^2 - 2 p.q), two j-points per packed register, 16 chains/read.
    #pragma unroll 2
    for (int j = 0; j < JTILE / 2; ++j) {
        float4 qv = sQ[j];
        v2f qx = (v2f){qv.x, qv.y};
        v2f qy = (v2f){qv.z, qv.w};
        v2f qq = __builtin_elementwise_fma(qx, qx, qy * qy);
        #pragma unroll
        for (int k = 0; k < IB; ++k) {
            v2f s = __builtin_elementwise_fma(m2y[k], qy, qq);
            s     = __builtin_elementwise_fma(m2x[k], qx, s);
            mn[k] = fminf(mn[k], fminf(s.x, s.y));   // v_min3_f32
        }
    }

    // Partial min for this j-chunk, |p|^2 restored. Layout: [dir][b][jc][i].
    float* dst = pw + (size_t)((dir * B + b) * JC + jc) * N;
    #pragma unroll
    for (int k = 0; k < IB; ++k)
        dst[t + k * TPB] = mn[k] + pp[k];
}

// One block per (i-tile, b, dir): min over 64 jc (coalesced), block max-reduce,
// atomicMax into a per-(dir,b) slot; the 256th block computes the final scalar.
// Cross-block protocol is atomics-only (device-coherent); the single lane-0
// __threadfence orders slot-write before counter-bump.
__global__ __launch_bounds__(TPB) void hk_maxred(const float* __restrict__ pw,
                                                 int* __restrict__ slots,  // [16]
                                                 int* __restrict__ cnt,    // [1]
                                                 float* __restrict__ out) {
    const int tile = blockIdx.x;
    const int b    = blockIdx.y;
    const int dir  = blockIdx.z;
    const int t    = threadIdx.x;

    const float* base = pw + (size_t)((dir * B + b) * JC) * N + tile * TPB + t;
    float mnv = base[0];
    #pragma unroll
    for (int jc = 1; jc < JC; ++jc) mnv = fminf(mnv, base[(size_t)jc * N]);

    float mx = mnv;
    #pragma unroll
    for (int off = 32; off > 0; off >>= 1)
        mx = fmaxf(mx, __shfl_down(mx, off, 64));

    __shared__ float sred[TPB / 64];
    __shared__ int sflag;
    if ((t & 63) == 0) sred[t >> 6] = mx;
    __syncthreads();
    if (t == 0) {
        float bm = sred[0];
        #pragma unroll
        for (int w = 1; w < TPB / 64; ++w) bm = fmaxf(bm, sred[w]);
        atomicMax(&slots[dir * B + b], __float_as_int(bm));  // bm >= 0
        __threadfence();                       // order slot-write before count
        int old = atomicAdd(cnt, 1);
        sflag = (old == RBLOCKS - 1);
    }
    __syncthreads();
    if (!sflag) return;

    // Last block of 256: all slots final (each predecessor fenced between its
    // slot atomicMax and its counter add). Atomic reads pull coherent values.
    __threadfence();
    __shared__ float sh2[2 * B];
    if (t < 2 * B) sh2[t] = __int_as_float(atomicMax(&slots[t], 0));
    __syncthreads();
    if (t == 0) {
        float s = 0.f;
        #pragma unroll
        for (int bb = 0; bb < B; ++bb)
            s += sqrtf(fmaxf(fmaxf(sh2[bb], sh2[B + bb]), 0.f));
        out[0] = s * (1.0f / B);
    }
}

extern "C" void kernel_launch(void* const* d_in, const int* in_sizes, int n_in,
                              void* d_out, int out_size, void* d_ws, size_t ws_size,
                              hipStream_t stream) {
    const float* pred   = (const float*)d_in[0];
    const float* target = (const float*)d_in[1];
    float* out = (float*)d_out;

    int*   slots = (int*)d_ws;                    // [16]
    int*   cnt   = (int*)d_ws + 16;               // [1]
    float* pw    = (float*)((char*)d_ws + 256);   // 2*8*64*4096 floats = 16 MB

    hipMemsetAsync(d_ws, 0, 128, stream);         // slots + cnt

    dim3 g1(JC, B, 2);           // 1024 blocks -> 4 blocks/CU, 16 waves/CU
    hk_partial<<<g1, TPB, 0, stream>>>(pred, target, pw);
    dim3 g2(ITILES, B, 2);       // 256 blocks
    hk_maxred<<<g2, TPB, 0, stream>>>(pw, slots, cnt, out);
}

// Round 9
// 89.139 us; speedup vs baseline: 1.1041x; 1.1041x over previous
//
#include <hip/hip_runtime.h>
#include <hip/hip_bf16.h>
#include <math.h>

// Symmetric Hausdorff, B=8, N=M=4096, D=2, fp32.
// Round 9: R8 minus the spill. R8's plan (packed fp32 + IB=16 so each
// ds_read_b128 feeds 16 pk min-chains; LDS pipe ~47%, 1.56 inst/pair) was
// right, but __launch_bounds__(256,4) under-allocated VGPRs for the ~115-reg
// demand -> scratch spills (WRITE_SIZE 55 MB, VALUBusy 0.5%, 130 us).
// Fix: no occupancy clamp; ~128 VGPRs fits naturally at 4 waves/SIMD.
// Pipeline: hk_partial (1024 blocks) -> hk_maxred (256, fused final via
// last-block + atomic slots). The ~42us fillBuffer in every profile is the
// harness poisoning the 256 MiB workspace inside the timed window.

#define B 8
#define N 4096
#define TPB 256
#define IB 16             // i-points per thread (covers all 4096 i per block)
#define JC 64             // j-chunks per (b,dir)
#define JTILE (N / JC)    // 64 j-points per block
#define ITILES (N / TPB)  // 16 i-tiles for the reduce stage
#define RBLOCKS (ITILES * B * 2)   // 256 reduce blocks

typedef float v2f __attribute__((ext_vector_type(2)));

__global__ __launch_bounds__(TPB) void hk_partial(const float* __restrict__ pred,
                                                  const float* __restrict__ target,
                                                  float* __restrict__ pw) {
    const int jc  = blockIdx.x;        // 0..63
    const int b   = blockIdx.y;
    const int dir = blockIdx.z;
    const int t   = threadIdx.x;

    const float2* __restrict__ P =
        reinterpret_cast<const float2*>(dir == 0 ? pred : target) + (size_t)b * N;
    const float*  __restrict__ Qf =
        (dir == 0 ? target : pred) + (size_t)b * N * 2 + (size_t)jc * JTILE * 2;

    // Stage 64 j-points as 32 float4, swizzled (x0,x1,y0,y1) so the packed
    // loop's qx/qy fall in adjacent VGPR pairs. 512 B LDS.
    __shared__ float4 sQ[JTILE / 2];
    if (t < JTILE / 2) {
        float4 g = reinterpret_cast<const float4*>(Qf)[t];   // x0,y0,x1,y1
        sQ[t] = make_float4(g.x, g.z, g.y, g.w);             // x0,x1,y0,y1
    }
    __syncthreads();

    // This thread's 16 source points (strided by TPB so pw stores coalesce).
    v2f m2x[IB], m2y[IB];
    float pp[IB], mn[IB];
    #pragma unroll
    for (int k = 0; k < IB; ++k) {
        float2 p = P[t + k * TPB];
        float ax = -2.f * p.x, ay = -2.f * p.y;
        m2x[k] = (v2f){ax, ax};
        m2y[k] = (v2f){ay, ay};
        pp[k]  = fmaf(p.x, p.x, p.y * p.y);
        mn[k]  = 3.402823466e38f;
    }

    // min_j(|q|^2 - 2 p.q), two j-points per packed register, 16 chains/read.
    // Per iter: 1 broadcast b128 + 2 pk (qq) + 16*(2 v_pk_fma_f32 + v_min3).
    #pragma unroll 2
    for (int j = 0; j < JTILE / 2; ++j) {
        float4 qv = sQ[j];
        v2f qx = (v2f){qv.x, qv.y};
        v2f qy = (v2f){qv.z, qv.w};
        v2f qq = __builtin_elementwise_fma(qx, qx, qy * qy);
        #pragma unroll
        for (int k = 0; k < IB; ++k) {
            v2f s = __builtin_elementwise_fma(m2y[k], qy, qq);
            s     = __builtin_elementwise_fma(m2x[k], qx, s);
            mn[k] = fminf(mn[k], fminf(s.x, s.y));   // v_min3_f32
        }
    }

    // Partial min for this j-chunk, |p|^2 restored. Layout: [dir][b][jc][i].
    float* dst = pw + (size_t)((dir * B + b) * JC + jc) * N;
    #pragma unroll
    for (int k = 0; k < IB; ++k)
        dst[t + k * TPB] = mn[k] + pp[k];
}

// One block per (i-tile, b, dir): min over 64 jc (coalesced), block max-reduce,
// atomicMax into a per-(dir,b) slot; the 256th block computes the final scalar.
// Cross-block protocol is atomics-only (device-coherent); the single lane-0
// __threadfence orders slot-write before counter-bump.
__global__ __launch_bounds__(TPB) void hk_maxred(const float* __restrict__ pw,
                                                 int* __restrict__ slots,  // [16]
                                                 int* __restrict__ cnt,    // [1]
                                                 float* __restrict__ out) {
    const int tile = blockIdx.x;
    const int b    = blockIdx.y;
    const int dir  = blockIdx.z;
    const int t    = threadIdx.x;

    const float* base = pw + (size_t)((dir * B + b) * JC) * N + tile * TPB + t;
    float mnv = base[0];
    #pragma unroll
    for (int jc = 1; jc < JC; ++jc) mnv = fminf(mnv, base[(size_t)jc * N]);

    float mx = mnv;
    #pragma unroll
    for (int off = 32; off > 0; off >>= 1)
        mx = fmaxf(mx, __shfl_down(mx, off, 64));

    __shared__ float sred[TPB / 64];
    __shared__ int sflag;
    if ((t & 63) == 0) sred[t >> 6] = mx;
    __syncthreads();
    if (t == 0) {
        float bm = sred[0];
        #pragma unroll
        for (int w = 1; w < TPB / 64; ++w) bm = fmaxf(bm, sred[w]);
        atomicMax(&slots[dir * B + b], __float_as_int(bm));  // bm >= 0
        __threadfence();                       // order slot-write before count
        int old = atomicAdd(cnt, 1);
        sflag = (old == RBLOCKS - 1);
    }
    __syncthreads();
    if (!sflag) return;

    // Last block of 256: all slots final (each predecessor fenced between its
    // slot atomicMax and its counter add). Atomic reads pull coherent values.
    __threadfence();
    __shared__ float sh2[2 * B];
    if (t < 2 * B) sh2[t] = __int_as_float(atomicMax(&slots[t], 0));
    __syncthreads();
    if (t == 0) {
        float s = 0.f;
        #pragma unroll
        for (int bb = 0; bb < B; ++bb)
            s += sqrtf(fmaxf(fmaxf(sh2[bb], sh2[B + bb]), 0.f));
        out[0] = s * (1.0f / B);
    }
}

extern "C" void kernel_launch(void* const* d_in, const int* in_sizes, int n_in,
                              void* d_out, int out_size, void* d_ws, size_t ws_size,
                              hipStream_t stream) {
    const float* pred   = (const float*)d_in[0];
    const float* target = (const float*)d_in[1];
    float* out = (float*)d_out;

    int*   slots = (int*)d_ws;                    // [16]
    int*   cnt   = (int*)d_ws + 16;               // [1]
    float* pw    = (float*)((char*)d_ws + 256);   // 2*8*64*4096 floats = 16 MB

    hipMemsetAsync(d_ws, 0, 128, stream);         // slots + cnt

    dim3 g1(JC, B, 2);           // 1024 blocks -> 4 blocks/CU, 16 waves/CU
    hk_partial<<<g1, TPB, 0, stream>>>(pred, target, pw);
    dim3 g2(ITILES, B, 2);       // 256 blocks
    hk_maxred<<<g2, TPB, 0, stream>>>(pw, slots, cnt, out);
}